// Round 2
// baseline (2245.556 us; speedup 1.0000x reference)
//
#include <hip/hip_runtime.h>

#define N_MET 100000
#define N_RXN 50000
#define E_SUB 2000000
#define E_ALL 4000000
#define MSG_DIM 16
#define HIDDEN 32

// Kernel 1: per-substrate-edge message MLP (2 -> 32 tanh -> 16) + atomic
// scatter-add into one of R replicas of h_rxn[N_RXN][MSG_DIM].
// Replication divides per-cacheline atomic contention (~640 ops/line at R=1) by R.
__global__ __launch_bounds__(256, 2) void msg_scatter_kernel(
    const float* __restrict__ x_met, const float* __restrict__ sto_sub,
    const float* __restrict__ W1m, const float* __restrict__ b1m,
    const float* __restrict__ W2m, const float* __restrict__ b2m,
    const int* __restrict__ met_sub, const int* __restrict__ rxn_sub,
    float* __restrict__ h_rep, int R)
{
    __shared__ float sW1[2 * HIDDEN];
    __shared__ float sb1[HIDDEN];
    __shared__ float sW2[HIDDEN * MSG_DIM];
    __shared__ float sb2[MSG_DIM];
    const int t = threadIdx.x;
    if (t < 2 * HIDDEN) sW1[t] = W1m[t];
    if (t < HIDDEN)     sb1[t] = b1m[t];
    for (int i = t; i < HIDDEN * MSG_DIM; i += 256) sW2[i] = W2m[i];
    if (t < MSG_DIM)    sb2[t] = b2m[t];
    __syncthreads();

    const int e = blockIdx.x * 256 + t;
    if (e >= E_SUB) return;

    const float x = x_met[met_sub[e]];
    const float s = sto_sub[e];

    float msg[MSG_DIM];
#pragma unroll
    for (int d = 0; d < MSG_DIM; ++d) msg[d] = sb2[d];

#pragma unroll
    for (int j = 0; j < HIDDEN; ++j) {
        const float h = tanhf(x * sW1[j] + s * sW1[HIDDEN + j] + sb1[j]);
#pragma unroll
        for (int d = 0; d < MSG_DIM; ++d)
            msg[d] += h * sW2[j * MSG_DIM + d];
    }

    const int rep = blockIdx.x % R;
    float* dst = h_rep + (size_t)rep * (N_RXN * MSG_DIM)
                       + (size_t)rxn_sub[e] * MSG_DIM;
#pragma unroll
    for (int d = 0; d < MSG_DIM; ++d)
        unsafeAtomicAdd(dst + d, msg[d]);
}

// Kernel 2: fold R replicas of h_rxn, then rate MLP (16 -> 32 tanh -> 1) + softplus.
__global__ __launch_bounds__(256) void rate_kernel(
    const float* __restrict__ h_rep,
    const float* __restrict__ W1r, const float* __restrict__ b1r,
    const float* __restrict__ W2r, const float* __restrict__ b2r,
    float* __restrict__ v, int R)
{
    __shared__ float sW1[MSG_DIM * HIDDEN];
    __shared__ float sb1[HIDDEN];
    __shared__ float sW2[HIDDEN];
    __shared__ float sb2;
    const int t = threadIdx.x;
    for (int i = t; i < MSG_DIM * HIDDEN; i += 256) sW1[i] = W1r[i];
    if (t < HIDDEN) { sb1[t] = b1r[t]; sW2[t] = W2r[t]; }
    if (t == 0) sb2 = b2r[0];
    __syncthreads();

    const int r = blockIdx.x * 256 + t;
    if (r >= N_RXN) return;

    float h[MSG_DIM];
#pragma unroll
    for (int d = 0; d < MSG_DIM; ++d) h[d] = 0.0f;
    for (int rep = 0; rep < R; ++rep) {
        const float* src = h_rep + (size_t)rep * (N_RXN * MSG_DIM) + (size_t)r * MSG_DIM;
#pragma unroll
        for (int d = 0; d < MSG_DIM; ++d) h[d] += src[d];
    }

    float acc = sb2;
#pragma unroll
    for (int j = 0; j < HIDDEN; ++j) {
        float z = sb1[j];
#pragma unroll
        for (int d = 0; d < MSG_DIM; ++d) z += h[d] * sW1[d * HIDDEN + j];
        acc += tanhf(z) * sW2[j];
    }
    v[r] = fmaxf(acc, 0.0f) + log1pf(expf(-fabsf(acc)));
}

// Kernel 3: per-all-edge contribution into one of R replicas of dxdt.
__global__ __launch_bounds__(256, 2) void contrib_scatter_kernel(
    const float* __restrict__ sto_all, const float* __restrict__ v,
    const int* __restrict__ met_all, const int* __restrict__ rxn_all,
    float* __restrict__ d_rep, int R)
{
    const int e = blockIdx.x * 256 + threadIdx.x;
    if (e >= E_ALL) return;
    const float c = sto_all[e] * v[rxn_all[e]];
    const int rep = blockIdx.x % R;
    unsafeAtomicAdd(d_rep + (size_t)rep * N_MET + met_all[e], c);
}

// Kernel 4: fold R replicas of dxdt into d_out.
__global__ __launch_bounds__(256) void dxdt_reduce_kernel(
    const float* __restrict__ d_rep, float* __restrict__ dxdt, int R)
{
    const int i = blockIdx.x * 256 + threadIdx.x;
    if (i >= N_MET) return;
    float acc = 0.0f;
    for (int rep = 0; rep < R; ++rep) acc += d_rep[(size_t)rep * N_MET + i];
    dxdt[i] = acc;
}

extern "C" void kernel_launch(void* const* d_in, const int* in_sizes, int n_in,
                              void* d_out, int out_size, void* d_ws, size_t ws_size,
                              hipStream_t stream) {
    const float* x_met   = (const float*)d_in[0];
    const float* sto_sub = (const float*)d_in[1];
    const float* sto_all = (const float*)d_in[2];
    const float* W1m     = (const float*)d_in[3];
    const float* b1m     = (const float*)d_in[4];
    const float* W2m     = (const float*)d_in[5];
    const float* b2m     = (const float*)d_in[6];
    const float* W1r     = (const float*)d_in[7];
    const float* b1r     = (const float*)d_in[8];
    const float* W2r     = (const float*)d_in[9];
    const float* b2r     = (const float*)d_in[10];
    const int*   met_sub = (const int*)d_in[11];
    const int*   rxn_sub = (const int*)d_in[12];
    const int*   met_all = (const int*)d_in[13];
    const int*   rxn_all = (const int*)d_in[14];

    float* dxdt = (float*)d_out;             // [N_MET]
    float* v    = dxdt + N_MET;              // [N_RXN]

    const size_t hbytes = (size_t)N_RXN * MSG_DIM * sizeof(float);  // 3.2 MB
    const size_t dbytes = (size_t)N_MET * sizeof(float);            // 0.4 MB

    // pick replica counts that fit the workspace
    int R = 8;
    while (R > 1 && (size_t)R * (hbytes + dbytes) > ws_size) R >>= 1;

    float* h_rep = (float*)d_ws;                                   // [R][N_RXN*MSG_DIM]
    float* d_rep = (float*)((char*)d_ws + (size_t)R * hbytes);     // [R][N_MET]

    hipMemsetAsync(d_ws, 0, (size_t)R * (hbytes + dbytes), stream);

    msg_scatter_kernel<<<(E_SUB + 255) / 256, 256, 0, stream>>>(
        x_met, sto_sub, W1m, b1m, W2m, b2m, met_sub, rxn_sub, h_rep, R);

    rate_kernel<<<(N_RXN + 255) / 256, 256, 0, stream>>>(
        h_rep, W1r, b1r, W2r, b2r, v, R);

    contrib_scatter_kernel<<<(E_ALL + 255) / 256, 256, 0, stream>>>(
        sto_all, v, met_all, rxn_all, d_rep, R);

    dxdt_reduce_kernel<<<(N_MET + 255) / 256, 256, 0, stream>>>(
        d_rep, dxdt, R);
}

// Round 3
// 1271.608 us; speedup vs baseline: 1.7659x; 1.7659x over previous
//
#include <hip/hip_runtime.h>

#define N_MET 100000
#define N_RXN 50000
#define E_SUB 2000000
#define E_ALL 4000000
#define MSG_DIM 16
#define HIDDEN 32

// Kernel 1: per-substrate-edge message MLP (2 -> 32 tanh -> 16), then
// LINE-COALESCED atomic scatter into h_rxn[N_RXN][16].
// One h_rxn row = 16 floats = exactly one 64B cacheline. Compute phase is
// 1 thread/edge (as round 1); msg vectors staged in LDS; atomic phase remaps
// lanes so one wave instruction = 4 edges x 16 consecutive dwords = 4 whole
// cachelines (vs 64 scattered lines/instr in rounds 1-2).
__global__ __launch_bounds__(256, 2) void msg_scatter_kernel(
    const float* __restrict__ x_met, const float* __restrict__ sto_sub,
    const float* __restrict__ W1m, const float* __restrict__ b1m,
    const float* __restrict__ W2m, const float* __restrict__ b2m,
    const int* __restrict__ met_sub, const int* __restrict__ rxn_sub,
    float* __restrict__ h_rxn)
{
    __shared__ float sW1[2 * HIDDEN];
    __shared__ float sb1[HIDDEN];
    __shared__ float sW2[HIDDEN * MSG_DIM];
    __shared__ float sb2[MSG_DIM];
    __shared__ __align__(16) float smsg[256 * MSG_DIM];   // 16 KB
    __shared__ int srxn[256];

    const int t = threadIdx.x;
    if (t < 2 * HIDDEN) sW1[t] = W1m[t];
    if (t < HIDDEN)     sb1[t] = b1m[t];
    for (int i = t; i < HIDDEN * MSG_DIM; i += 256) sW2[i] = W2m[i];
    if (t < MSG_DIM)    sb2[t] = b2m[t];
    __syncthreads();

    const int e0 = blockIdx.x * 256;
    const int e  = e0 + t;
    if (e < E_SUB) {
        const float x = x_met[met_sub[e]];
        const float s = sto_sub[e];
        float msg[MSG_DIM];
#pragma unroll
        for (int d = 0; d < MSG_DIM; ++d) msg[d] = sb2[d];
#pragma unroll
        for (int j = 0; j < HIDDEN; ++j) {
            const float h = tanhf(fmaf(x, sW1[j], fmaf(s, sW1[HIDDEN + j], sb1[j])));
#pragma unroll
            for (int d = 0; d < MSG_DIM; ++d)
                msg[d] = fmaf(h, sW2[j * MSG_DIM + d], msg[d]);
        }
        srxn[t] = rxn_sub[e];
        float4* dst = (float4*)&smsg[t * MSG_DIM];
        dst[0] = make_float4(msg[0],  msg[1],  msg[2],  msg[3]);
        dst[1] = make_float4(msg[4],  msg[5],  msg[6],  msg[7]);
        dst[2] = make_float4(msg[8],  msg[9],  msg[10], msg[11]);
        dst[3] = make_float4(msg[12], msg[13], msg[14], msg[15]);
    }
    __syncthreads();

    // Atomic phase: wave w owns local edges [w*64, w*64+64). Lane l handles
    // edge-subgroup g = l>>4, channel d = l&15. Per iteration, the wave's 64
    // lanes cover 4 edges' full 16-dword rows (4 cachelines).
    const int w = t >> 6;
    const int l = t & 63;
    const int g = l >> 4;
    const int d = l & 15;
#pragma unroll
    for (int it = 0; it < 16; ++it) {
        const int le = w * 64 + it * 4 + g;
        const int ge = e0 + le;
        if (ge < E_SUB)
            unsafeAtomicAdd(h_rxn + (size_t)srxn[le] * MSG_DIM + d,
                            smsg[le * MSG_DIM + d]);
    }
}

// Kernel 2: per-reaction rate MLP (16 -> 32 tanh -> 1) + softplus -> v.
__global__ __launch_bounds__(256) void rate_kernel(
    const float* __restrict__ h_rxn,
    const float* __restrict__ W1r, const float* __restrict__ b1r,
    const float* __restrict__ W2r, const float* __restrict__ b2r,
    float* __restrict__ v)
{
    __shared__ float sW1[MSG_DIM * HIDDEN];
    __shared__ float sb1[HIDDEN];
    __shared__ float sW2[HIDDEN];
    __shared__ float sb2;
    const int t = threadIdx.x;
    for (int i = t; i < MSG_DIM * HIDDEN; i += 256) sW1[i] = W1r[i];
    if (t < HIDDEN) { sb1[t] = b1r[t]; sW2[t] = W2r[t]; }
    if (t == 0) sb2 = b2r[0];
    __syncthreads();

    const int r = blockIdx.x * 256 + t;
    if (r >= N_RXN) return;

    float h[MSG_DIM];
#pragma unroll
    for (int d = 0; d < MSG_DIM; ++d) h[d] = h_rxn[(size_t)r * MSG_DIM + d];

    float acc = sb2;
#pragma unroll
    for (int j = 0; j < HIDDEN; ++j) {
        float z = sb1[j];
#pragma unroll
        for (int d = 0; d < MSG_DIM; ++d) z = fmaf(h[d], sW1[d * HIDDEN + j], z);
        acc = fmaf(tanhf(z), sW2[j], acc);
    }
    v[r] = fmaxf(acc, 0.0f) + log1pf(expf(-fabsf(acc)));
}

// Kernel 3: per-all-edge contribution scattered into dxdt (direct, R=1 —
// replication proved neutral in round 2; this is atomic-service-rate bound).
__global__ __launch_bounds__(256, 2) void contrib_scatter_kernel(
    const float* __restrict__ sto_all, const float* __restrict__ v,
    const int* __restrict__ met_all, const int* __restrict__ rxn_all,
    float* __restrict__ dxdt)
{
    const int e = blockIdx.x * 256 + threadIdx.x;
    if (e >= E_ALL) return;
    const float c = sto_all[e] * v[rxn_all[e]];
    unsafeAtomicAdd(dxdt + met_all[e], c);
}

extern "C" void kernel_launch(void* const* d_in, const int* in_sizes, int n_in,
                              void* d_out, int out_size, void* d_ws, size_t ws_size,
                              hipStream_t stream) {
    const float* x_met   = (const float*)d_in[0];
    const float* sto_sub = (const float*)d_in[1];
    const float* sto_all = (const float*)d_in[2];
    const float* W1m     = (const float*)d_in[3];
    const float* b1m     = (const float*)d_in[4];
    const float* W2m     = (const float*)d_in[5];
    const float* b2m     = (const float*)d_in[6];
    const float* W1r     = (const float*)d_in[7];
    const float* b1r     = (const float*)d_in[8];
    const float* W2r     = (const float*)d_in[9];
    const float* b2r     = (const float*)d_in[10];
    const int*   met_sub = (const int*)d_in[11];
    const int*   rxn_sub = (const int*)d_in[12];
    const int*   met_all = (const int*)d_in[13];
    const int*   rxn_all = (const int*)d_in[14];

    float* dxdt  = (float*)d_out;            // [N_MET]
    float* v     = dxdt + N_MET;             // [N_RXN]
    float* h_rxn = (float*)d_ws;             // [N_RXN * MSG_DIM]

    hipMemsetAsync(dxdt, 0, (size_t)N_MET * sizeof(float), stream);
    hipMemsetAsync(h_rxn, 0, (size_t)N_RXN * MSG_DIM * sizeof(float), stream);

    msg_scatter_kernel<<<(E_SUB + 255) / 256, 256, 0, stream>>>(
        x_met, sto_sub, W1m, b1m, W2m, b2m, met_sub, rxn_sub, h_rxn);

    rate_kernel<<<(N_RXN + 255) / 256, 256, 0, stream>>>(
        h_rxn, W1r, b1r, W2r, b2r, v);

    contrib_scatter_kernel<<<(E_ALL + 255) / 256, 256, 0, stream>>>(
        sto_all, v, met_all, rxn_all, dxdt);
}